// Round 3
// baseline (242.350 us; speedup 1.0000x reference)
//
#include <hip/hip_runtime.h>
#include <hip/hip_bf16.h>
#include <cstdint>

#define NEG_BIG (-1.0e9f)

typedef __attribute__((ext_vector_type(8))) short short8_t;
typedef __attribute__((ext_vector_type(4))) float f32x4;

__device__ __forceinline__ short f2bf(float x) {
  union { float f; unsigned u; } v; v.f = x;
  unsigned r = v.u + 0x7fffu + ((v.u >> 16) & 1u);
  return (short)(r >> 16);
}
__device__ __forceinline__ float sigmoidf_(float x) { return 1.0f / (1.0f + __expf(-x)); }

// ---------------- K0: pack A1 = [emb[prev] | h0] as bf16, rows of 1536 ----------------
__global__ void k_pack_a1(const int* __restrict__ prev, const float* __restrict__ emb,
                          const float* __restrict__ h0, short* __restrict__ A1) {
  int t = blockIdx.x * 256 + threadIdx.x;
  if (t >= 128 * 1536) return;
  int b = t / 1536, k = t - b * 1536;
  float v = (k < 512) ? emb[(size_t)prev[b] * 512 + k] : h0[b * 1024 + (k - 512)];
  A1[t] = f2bf(v);
}

// ------- M-tiled bf16-MFMA GEMM with 2-phase reg-staged pipeline ------------
// C[128][N] = A(bf16)[128][Ktot] @ W(f32)[N][Ktot]^T
// MB: rows per block (128 or 64); grid.y = 128/MB.
// WN=1: BN=16, 4 waves split M. WN=4: BN=64, waves split N (MREP=8).
// K window spans [Wa (Ka cols) | Wb]. EPI 0: f32 out + bias; EPI 1: bf16 tanh out.
template <int MB, int WN, int EPI>
__launch_bounds__(256, 2)
__global__ void k_gemm(const short* __restrict__ A, int lda,
                       const float* __restrict__ Wa, int ldwa, int Ka,
                       const float* __restrict__ Wb, int ldwb, int Ktot,
                       const float* __restrict__ bias0, const float* __restrict__ bias1,
                       float* __restrict__ outF, short* __restrict__ outB, int ldo) {
  constexpr int BN = WN * 16;
  constexpr int MREP = (MB == 128) ? 2 * WN : 1;
  constexpr int AU = MB / 32;                 // short8 units per thread (A stage)
  constexpr int WLOADS = (BN * 64) / 1024;    // float4 loads per thread (W stage)
  __shared__ __align__(16) short lA[2][MB * 64];
  __shared__ __align__(16) short lW[2][BN * 64];
  const int tid = threadIdx.x;
  const int wid = tid >> 6, l = tid & 63, l15 = l & 15, khalf = l >> 4;
  const int nblk = blockIdx.x;
  const int mrow0 = blockIdx.y * MB;
  const int m_wave = (WN == 1) ? wid * (MB / 4) : 0;
  const int nb_local = (WN == 4) ? wid * 16 : 0;

  // A staging geometry: MB=128 -> 2 thr/row x 4 units; MB=64 -> 4 thr/row x 2 units
  const int arow = (MB == 128) ? (tid >> 1) : (tid >> 2);
  const int apart = (MB == 128) ? (tid & 1) : (tid & 3);
  const int abase = apart * (AU * 16);        // byte base within 128B LDS row
  const int aswz = (arow & 7) << 4;
  const short* Arow = A + (size_t)(mrow0 + arow) * lda + apart * (AU * 8);

  // W staging geometry (per-thread constant n,kq per j)
  int wn_[WLOADS], wkq_[WLOADS];
#pragma unroll
  for (int j = 0; j < WLOADS; ++j) {
    int idx = j * 1024 + tid * 4;
    wn_[j] = idx >> 6;
    wkq_[j] = idx & 63;
  }

  f32x4 acc[MREP];
#pragma unroll
  for (int r = 0; r < MREP; ++r) acc[r] = (f32x4){0.f, 0.f, 0.f, 0.f};

  short8_t aR[AU];
  float4 wR[WLOADS];

  auto stage_regs = [&](int k0) {
#pragma unroll
    for (int q = 0; q < AU; ++q) aR[q] = *(const short8_t*)(Arow + k0 + q * 8);
#pragma unroll
    for (int j = 0; j < WLOADS; ++j) {
      int kg = k0 + wkq_[j];
      const float* p = (kg < Ka) ? (Wa + (size_t)(nblk * BN + wn_[j]) * ldwa + kg)
                                 : (Wb + (size_t)(nblk * BN + wn_[j]) * ldwb + (kg - Ka));
      wR[j] = *(const float4*)p;
    }
  };
  auto write_lds = [&](int buf) {
    char* drow = (char*)lA[buf] + arow * 128;
#pragma unroll
    for (int q = 0; q < AU; ++q)
      *(short8_t*)(drow + ((abase + q * 16) ^ aswz)) = aR[q];
#pragma unroll
    for (int j = 0; j < WLOADS; ++j) {
      short4 h4;
      h4.x = f2bf(wR[j].x); h4.y = f2bf(wR[j].y); h4.z = f2bf(wR[j].z); h4.w = f2bf(wR[j].w);
      *(short4*)((char*)lW[buf] + wn_[j] * 128 + ((wkq_[j] * 2) ^ ((wn_[j] & 7) << 4))) = h4;
    }
  };
  auto compute = [&](int buf) {
#pragma unroll
    for (int ks = 0; ks < 2; ++ks) {
      const int ubyte = ks * 64 + khalf * 16;
      const int nrow = nb_local + l15;
      short8_t bfrag = *(const short8_t*)((char*)lW[buf] + nrow * 128 + (ubyte ^ ((nrow & 7) << 4)));
#pragma unroll
      for (int r = 0; r < MREP; ++r) {
        const int mrow = m_wave + r * 16 + l15;
        short8_t afrag = *(const short8_t*)((char*)lA[buf] + mrow * 128 + (ubyte ^ ((mrow & 7) << 4)));
        acc[r] = __builtin_amdgcn_mfma_f32_16x16x32_bf16(afrag, bfrag, acc[r], 0, 0, 0);
      }
    }
  };

  const int NT = Ktot >> 6;
  stage_regs(0);
  write_lds(0);
  for (int t = 0; t < NT; ++t) {
    const int cur = t & 1;
    if (t + 1 < NT) stage_regs((t + 1) << 6);   // loads in flight across barrier
    __syncthreads();                            // buf[cur] ready
    compute(cur);
    if (t + 1 < NT) write_lds(cur ^ 1);         // other buffer; safe (see barrier)
  }

  const int n = nblk * BN + nb_local + l15;
  float bias = 0.f;
  if (bias0) bias = bias0[n];
  if (bias1) bias += bias1[n];
#pragma unroll
  for (int r = 0; r < MREP; ++r) {
    int mb = mrow0 + m_wave + r * 16 + khalf * 4;
#pragma unroll
    for (int e = 0; e < 4; ++e) {
      float v = acc[r][e] + bias;
      if (EPI == 1) {
        outB[(size_t)(mb + e) * ldo + n] = f2bf(tanhf(v));
      } else {
        outF[(size_t)(mb + e) * ldo + n] = v;
      }
    }
  }
}

// ---------------- K2: LSTM elementwise ----------------
__global__ void k_lstm(const float* __restrict__ gates, const float* __restrict__ c0,
                       float* __restrict__ h1_out, float* __restrict__ c1_out,
                       short* __restrict__ A3) {
  int t = blockIdx.x * 256 + threadIdx.x;  // 131072
  int b = t >> 10, h = t & 1023;
  const float* g = gates + (size_t)b * 4096;
  float ig = sigmoidf_(g[h]);
  float fg = sigmoidf_(g[1024 + h]);
  float gg = tanhf(g[2048 + h]);
  float og = sigmoidf_(g[3072 + h]);
  float c1 = fg * c0[t] + ig * gg;
  float h1 = og * tanhf(c1);
  c1_out[t] = c1;
  h1_out[t] = h1;
  A3[(size_t)b * 2048 + 1024 + h] = f2bf(h1);  // second half of concat row
}

// ---------------- K4: flash attention pass (ctx read ONCE) ----------------
// grid 1024: b = bid>>3, chunk = bid&7 (64 s each); each wave owns 16 s, 2-row unroll.
__global__ void k_attn(const float* __restrict__ ctx, const float* __restrict__ target,
                       const unsigned char* __restrict__ mask,
                       float* __restrict__ scores, float* __restrict__ part) {
  int b = blockIdx.x >> 3, chunk = blockIdx.x & 7;
  int wid = threadIdx.x >> 6, l = threadIdx.x & 63;
  const float* tg = target + (size_t)b * 1024;
  float4 t4[4], w4[4];
#pragma unroll
  for (int j = 0; j < 4; ++j) {
    t4[j] = *(const float4*)(tg + j * 256 + l * 4);
    w4[j].x = 0.f; w4[j].y = 0.f; w4[j].z = 0.f; w4[j].w = 0.f;
  }
  float m = -INFINITY, lsum = 0.f;
  const int s0 = chunk * 64 + wid * 16;
  const float* cb = ctx + ((size_t)b * 512 + s0) * 1024;
  const unsigned char* mk = mask + (size_t)b * 512 + s0;
  for (int ss = 0; ss < 16; ss += 2) {
    const float* rowA = cb + (size_t)ss * 1024;
    const float* rowB = rowA + 1024;
    float4 c4a[4], c4b[4];
    float p0 = 0.f, p1 = 0.f;
#pragma unroll
    for (int j = 0; j < 4; ++j) {
      c4a[j] = *(const float4*)(rowA + j * 256 + l * 4);
      c4b[j] = *(const float4*)(rowB + j * 256 + l * 4);
      p0 += c4a[j].x * t4[j].x + c4a[j].y * t4[j].y + c4a[j].z * t4[j].z + c4a[j].w * t4[j].w;
      p1 += c4b[j].x * t4[j].x + c4b[j].y * t4[j].y + c4b[j].z * t4[j].z + c4b[j].w * t4[j].w;
    }
#pragma unroll
    for (int off = 32; off > 0; off >>= 1) {
      p0 += __shfl_xor(p0, off);
      p1 += __shfl_xor(p1, off);
    }
    if (mk[ss]) p0 = NEG_BIG;
    if (mk[ss + 1]) p1 = NEG_BIG;
    if (l == 0) {
      scores[(size_t)b * 512 + s0 + ss] = p0;
      scores[(size_t)b * 512 + s0 + ss + 1] = p1;
    }
    float mn = fmaxf(m, fmaxf(p0, p1));
    float scale = __expf(m - mn);
    float e0 = __expf(p0 - mn);
    float e1 = __expf(p1 - mn);
    lsum = lsum * scale + e0 + e1;
#pragma unroll
    for (int j = 0; j < 4; ++j) {
      w4[j].x = w4[j].x * scale + e0 * c4a[j].x + e1 * c4b[j].x;
      w4[j].y = w4[j].y * scale + e0 * c4a[j].y + e1 * c4b[j].y;
      w4[j].z = w4[j].z * scale + e0 * c4a[j].z + e1 * c4b[j].z;
      w4[j].w = w4[j].w * scale + e0 * c4a[j].w + e1 * c4b[j].w;
    }
    m = mn;
  }
  float* pp = part + ((size_t)b * 32 + (chunk * 4 + wid)) * 1028;
#pragma unroll
  for (int j = 0; j < 4; ++j) *(float4*)(pp + j * 256 + l * 4) = w4[j];
  if (l == 0) { pp[1024] = m; pp[1025] = lsum; }
}

// ------- K5: finish = exact alpha (from partial m/l) + combine partials -------
__global__ void k_finish(const float* __restrict__ scores, const float* __restrict__ part,
                         float* __restrict__ alpha, short* __restrict__ A3) {
  __shared__ float sm[32], sl[32];
  int b = blockIdx.x, t = threadIdx.x;
  if (t < 32) {
    sm[t] = part[((size_t)b * 32 + t) * 1028 + 1024];
    sl[t] = part[((size_t)b * 32 + t) * 1028 + 1025];
  }
  __syncthreads();
  float M = -INFINITY;
#pragma unroll
  for (int i = 0; i < 32; ++i) M = fmaxf(M, sm[i]);
  float scl[32];
  float L = 0.f;
#pragma unroll
  for (int i = 0; i < 32; ++i) {
    scl[i] = __expf(sm[i] - M);
    L += sl[i] * scl[i];
  }
  float inv = 1.0f / L;
  // exact alpha from raw scores: softmax max M and denom L match the reference
  float s0 = scores[(size_t)b * 512 + t];
  float s1 = scores[(size_t)b * 512 + 256 + t];
  alpha[(size_t)b * 512 + t] = __expf(s0 - M) * inv;
  alpha[(size_t)b * 512 + 256 + t] = __expf(s1 - M) * inv;
  // combine weighted partials (h = t*4)
  float ax = 0.f, ay = 0.f, az = 0.f, aw = 0.f;
#pragma unroll
  for (int i = 0; i < 32; ++i) {
    const float4 w = *(const float4*)(part + ((size_t)b * 32 + i) * 1028 + t * 4);
    ax += scl[i] * w.x; ay += scl[i] * w.y; az += scl[i] * w.z; aw += scl[i] * w.w;
  }
  short4 o4;
  o4.x = f2bf(ax * inv); o4.y = f2bf(ay * inv); o4.z = f2bf(az * inv); o4.w = f2bf(aw * inv);
  *(short4*)(A3 + (size_t)b * 2048 + t * 4) = o4;
}

extern "C" void kernel_launch(void* const* d_in, const int* in_sizes, int n_in,
                              void* d_out, int out_size, void* d_ws, size_t ws_size,
                              hipStream_t stream) {
  const int* prev = (const int*)d_in[0];
  const float* h0 = (const float*)d_in[1];
  const float* c0 = (const float*)d_in[2];
  const float* ctx = (const float*)d_in[3];
  const unsigned char* mask = (const unsigned char*)d_in[4];
  const float* emb = (const float*)d_in[5];
  const float* W_ih = (const float*)d_in[6];
  const float* W_hh = (const float*)d_in[7];
  const float* b_ih = (const float*)d_in[8];
  const float* b_hh = (const float*)d_in[9];
  const float* W_in = (const float*)d_in[10];
  const float* W_out = (const float*)d_in[11];
  const float* W_dec = (const float*)d_in[12];
  const float* b_dec = (const float*)d_in[13];

  float* out_h1 = (float*)d_out;            // 128*1024
  float* out_c1 = out_h1 + 128 * 1024;      // 128*1024
  float* out_alpha = out_c1 + 128 * 1024;   // 128*512
  float* out_logit = out_alpha + 128 * 512; // 128*32000

  char* ws = (char*)d_ws;
  short* A1 = (short*)(ws + 0x000000);      // 128x1536 bf16 (384KB)
  float* gates = (float*)(ws + 0x060000);   // 128x4096 f32  (2MB)
  short* A3 = (short*)(ws + 0x260000);      // 128x2048 bf16 [weighted | h1] (512KB)
  float* target = (float*)(ws + 0x2E0000);  // 128x1024 f32  (512KB)
  float* scores = (float*)(ws + 0x360000);  // 128x512 f32   (256KB)
  float* part = (float*)(ws + 0x3A0000);    // 128x32x1028 f32 (16.8MB)
  short* htilde = (short*)(ws + 0x1400000); // 128x1024 bf16 (256KB)

  // 1) pack gather+h0 operand
  k_pack_a1<<<768, 256, 0, stream>>>(prev, emb, h0, A1);
  // 2) gates = [emb|h0] @ [W_ih|W_hh]^T + b_ih + b_hh   (N=4096, K=1536)
  k_gemm<128, 1, 0><<<dim3(256, 1), 256, 0, stream>>>(A1, 1536, W_ih, 512, 512, W_hh, 1024,
                                                      1536, b_ih, b_hh, gates, nullptr, 4096);
  // 3) LSTM cell -> h_1, c_1 (+ bf16 h1 into A3 second half)
  k_lstm<<<512, 256, 0, stream>>>(gates, c0, out_h1, out_c1, A3);
  // 4) target = h1 @ W_in^T (N=1024, K=1024), M-split x2
  k_gemm<64, 1, 0><<<dim3(64, 2), 256, 0, stream>>>(A3 + 1024, 2048, W_in, 1024, 1024, W_in,
                                                    1024, 1024, nullptr, nullptr, target,
                                                    nullptr, 1024);
  // 5) flash attention over ctx (read once): scores + online partials
  k_attn<<<1024, 256, 0, stream>>>(ctx, target, mask, scores, part);
  // 6) alpha + combine partials -> weighted (bf16 into A3 first half)
  k_finish<<<128, 256, 0, stream>>>(scores, part, out_alpha, A3);
  // 7) h_tilde = tanh([weighted|h1] @ W_out^T) (N=1024, K=2048), bf16 out, M-split x2
  k_gemm<64, 1, 1><<<dim3(64, 2), 256, 0, stream>>>(A3, 2048, W_out, 2048, 2048, W_out, 2048,
                                                    2048, nullptr, nullptr, nullptr, htilde,
                                                    1024);
  // 8) logit = h_tilde @ W_dec^T + b_dec (N=32000, K=1024)
  k_gemm<128, 4, 0><<<dim3(500, 1), 256, 0, stream>>>(htilde, 1024, W_dec, 1024, 1024, W_dec,
                                                      1024, 1024, b_dec, nullptr, out_logit,
                                                      nullptr, 32000);
}

// Round 4
// 237.018 us; speedup vs baseline: 1.0225x; 1.0225x over previous
//
#include <hip/hip_runtime.h>
#include <hip/hip_bf16.h>
#include <cstdint>

#define NEG_BIG (-1.0e9f)

typedef __attribute__((ext_vector_type(8))) short short8_t;
typedef __attribute__((ext_vector_type(4))) float f32x4;

__device__ __forceinline__ short f2bf(float x) {
  union { float f; unsigned u; } v; v.f = x;
  unsigned r = v.u + 0x7fffu + ((v.u >> 16) & 1u);
  return (short)(r >> 16);
}
__device__ __forceinline__ float sigmoidf_(float x) { return 1.0f / (1.0f + __expf(-x)); }

// ---------------- K0: pack A1 = [emb[prev] | h0] as bf16, rows of 1536 ----------------
__global__ void k_pack_a1(const int* __restrict__ prev, const float* __restrict__ emb,
                          const float* __restrict__ h0, short* __restrict__ A1) {
  int t = blockIdx.x * 256 + threadIdx.x;
  if (t >= 128 * 1536) return;
  int b = t / 1536, k = t - b * 1536;
  float v = (k < 512) ? emb[(size_t)prev[b] * 512 + k] : h0[b * 1024 + (k - 512)];
  A1[t] = f2bf(v);
}

// ------- M-tiled bf16-MFMA GEMM with 2-phase reg-staged pipeline ------------
// C[128][N] = A(bf16)[128][Ktot] @ W(f32)[N][Ktot]^T
// MB: rows per block (128 or 64); grid.y = 128/MB.
// WN=1: BN=16, 4 waves split M. WN=4: BN=64, waves split N (MREP=8).
// K window spans [Wa (Ka cols) | Wb]. EPI 0: f32 out + bias; EPI 1: bf16 tanh out.
template <int MB, int WN, int EPI>
__launch_bounds__(256, 2)
__global__ void k_gemm(const short* __restrict__ A, int lda,
                       const float* __restrict__ Wa, int ldwa, int Ka,
                       const float* __restrict__ Wb, int ldwb, int Ktot,
                       const float* __restrict__ bias0, const float* __restrict__ bias1,
                       float* __restrict__ outF, short* __restrict__ outB, int ldo) {
  constexpr int BN = WN * 16;
  constexpr int MREP = (MB == 128) ? 2 * WN : 1;
  constexpr int AU = MB / 32;                 // short8 units per thread (A stage)
  constexpr int WLOADS = (BN * 64) / 1024;    // float4 loads per thread (W stage)
  __shared__ __align__(16) short lA[2][MB * 64];
  __shared__ __align__(16) short lW[2][BN * 64];
  const int tid = threadIdx.x;
  const int wid = tid >> 6, l = tid & 63, l15 = l & 15, khalf = l >> 4;
  const int nblk = blockIdx.x;
  const int mrow0 = blockIdx.y * MB;
  const int m_wave = (WN == 1) ? wid * (MB / 4) : 0;
  const int nb_local = (WN == 4) ? wid * 16 : 0;

  // A staging geometry: MB=128 -> 2 thr/row x 4 units; MB=64 -> 4 thr/row x 2 units
  const int arow = (MB == 128) ? (tid >> 1) : (tid >> 2);
  const int apart = (MB == 128) ? (tid & 1) : (tid & 3);
  const int abase = apart * (AU * 16);        // byte base within 128B LDS row
  const int aswz = (arow & 7) << 4;
  const short* Arow = A + (size_t)(mrow0 + arow) * lda + apart * (AU * 8);

  // W staging geometry (per-thread constant n,kq per j)
  int wn_[WLOADS], wkq_[WLOADS];
#pragma unroll
  for (int j = 0; j < WLOADS; ++j) {
    int idx = j * 1024 + tid * 4;
    wn_[j] = idx >> 6;
    wkq_[j] = idx & 63;
  }

  f32x4 acc[MREP];
#pragma unroll
  for (int r = 0; r < MREP; ++r) acc[r] = (f32x4){0.f, 0.f, 0.f, 0.f};

  short8_t aR[AU];
  float4 wR[WLOADS];

  auto stage_regs = [&](int k0) {
#pragma unroll
    for (int q = 0; q < AU; ++q) aR[q] = *(const short8_t*)(Arow + k0 + q * 8);
#pragma unroll
    for (int j = 0; j < WLOADS; ++j) {
      int kg = k0 + wkq_[j];
      const float* p = (kg < Ka) ? (Wa + (size_t)(nblk * BN + wn_[j]) * ldwa + kg)
                                 : (Wb + (size_t)(nblk * BN + wn_[j]) * ldwb + (kg - Ka));
      wR[j] = *(const float4*)p;
    }
  };
  auto write_lds = [&](int buf) {
    char* drow = (char*)lA[buf] + arow * 128;
#pragma unroll
    for (int q = 0; q < AU; ++q)
      *(short8_t*)(drow + ((abase + q * 16) ^ aswz)) = aR[q];
#pragma unroll
    for (int j = 0; j < WLOADS; ++j) {
      short4 h4;
      h4.x = f2bf(wR[j].x); h4.y = f2bf(wR[j].y); h4.z = f2bf(wR[j].z); h4.w = f2bf(wR[j].w);
      *(short4*)((char*)lW[buf] + wn_[j] * 128 + ((wkq_[j] * 2) ^ ((wn_[j] & 7) << 4))) = h4;
    }
  };
  auto compute = [&](int buf) {
#pragma unroll
    for (int ks = 0; ks < 2; ++ks) {
      const int ubyte = ks * 64 + khalf * 16;
      const int nrow = nb_local + l15;
      short8_t bfrag = *(const short8_t*)((char*)lW[buf] + nrow * 128 + (ubyte ^ ((nrow & 7) << 4)));
#pragma unroll
      for (int r = 0; r < MREP; ++r) {
        const int mrow = m_wave + r * 16 + l15;
        short8_t afrag = *(const short8_t*)((char*)lA[buf] + mrow * 128 + (ubyte ^ ((mrow & 7) << 4)));
        acc[r] = __builtin_amdgcn_mfma_f32_16x16x32_bf16(afrag, bfrag, acc[r], 0, 0, 0);
      }
    }
  };

  const int NT = Ktot >> 6;
  stage_regs(0);
  write_lds(0);
  for (int t = 0; t < NT; ++t) {
    const int cur = t & 1;
    if (t + 1 < NT) stage_regs((t + 1) << 6);   // loads in flight across barrier
    __syncthreads();                            // buf[cur] ready
    compute(cur);
    if (t + 1 < NT) write_lds(cur ^ 1);         // other buffer; safe (see barrier)
  }

  const int n = nblk * BN + nb_local + l15;
  float bias = 0.f;
  if (bias0) bias = bias0[n];
  if (bias1) bias += bias1[n];
#pragma unroll
  for (int r = 0; r < MREP; ++r) {
    int mb = mrow0 + m_wave + r * 16 + khalf * 4;
#pragma unroll
    for (int e = 0; e < 4; ++e) {
      float v = acc[r][e] + bias;
      if (EPI == 1) {
        outB[(size_t)(mb + e) * ldo + n] = f2bf(tanhf(v));
      } else {
        outF[(size_t)(mb + e) * ldo + n] = v;
      }
    }
  }
}

// ---------------- K2: LSTM elementwise ----------------
__global__ void k_lstm(const float* __restrict__ gates, const float* __restrict__ c0,
                       float* __restrict__ h1_out, float* __restrict__ c1_out,
                       short* __restrict__ A3) {
  int t = blockIdx.x * 256 + threadIdx.x;  // 131072
  int b = t >> 10, h = t & 1023;
  const float* g = gates + (size_t)b * 4096;
  float ig = sigmoidf_(g[h]);
  float fg = sigmoidf_(g[1024 + h]);
  float gg = tanhf(g[2048 + h]);
  float og = sigmoidf_(g[3072 + h]);
  float c1 = fg * c0[t] + ig * gg;
  float h1 = og * tanhf(c1);
  c1_out[t] = c1;
  h1_out[t] = h1;
  A3[(size_t)b * 2048 + 1024 + h] = f2bf(h1);  // second half of concat row
}

// ---------------- K4: flash attention pass (ctx read ONCE) ----------------
// grid 1024: b = bid>>3, chunk = bid&7 (64 s each); each wave owns 16 s, 2-row unroll.
// __launch_bounds__(256,4): VGPR cap 128 (not default-64) -- round-3 spill fix.
__launch_bounds__(256, 4)
__global__ void k_attn(const float* __restrict__ ctx, const float* __restrict__ target,
                       const unsigned char* __restrict__ mask,
                       float* __restrict__ scores, float* __restrict__ part) {
  int b = blockIdx.x >> 3, chunk = blockIdx.x & 7;
  int wid = threadIdx.x >> 6, l = threadIdx.x & 63;
  const float* tg = target + (size_t)b * 1024;
  float4 t4[4], w4[4];
#pragma unroll
  for (int j = 0; j < 4; ++j) {
    t4[j] = *(const float4*)(tg + j * 256 + l * 4);
    w4[j].x = 0.f; w4[j].y = 0.f; w4[j].z = 0.f; w4[j].w = 0.f;
  }
  float m = -INFINITY, lsum = 0.f;
  const int s0 = chunk * 64 + wid * 16;
  const float* cb = ctx + ((size_t)b * 512 + s0) * 1024;
  const unsigned char* mk = mask + (size_t)b * 512 + s0;
  for (int ss = 0; ss < 16; ss += 2) {
    const float* rowA = cb + (size_t)ss * 1024;
    const float* rowB = rowA + 1024;
    float4 c4a[4], c4b[4];
    float p0 = 0.f, p1 = 0.f;
#pragma unroll
    for (int j = 0; j < 4; ++j) {
      c4a[j] = *(const float4*)(rowA + j * 256 + l * 4);
      c4b[j] = *(const float4*)(rowB + j * 256 + l * 4);
      p0 += c4a[j].x * t4[j].x + c4a[j].y * t4[j].y + c4a[j].z * t4[j].z + c4a[j].w * t4[j].w;
      p1 += c4b[j].x * t4[j].x + c4b[j].y * t4[j].y + c4b[j].z * t4[j].z + c4b[j].w * t4[j].w;
    }
#pragma unroll
    for (int off = 32; off > 0; off >>= 1) {
      p0 += __shfl_xor(p0, off);
      p1 += __shfl_xor(p1, off);
    }
    if (mk[ss]) p0 = NEG_BIG;
    if (mk[ss + 1]) p1 = NEG_BIG;
    if (l == 0) {
      scores[(size_t)b * 512 + s0 + ss] = p0;
      scores[(size_t)b * 512 + s0 + ss + 1] = p1;
    }
    float mn = fmaxf(m, fmaxf(p0, p1));
    float scale = __expf(m - mn);
    float e0 = __expf(p0 - mn);
    float e1 = __expf(p1 - mn);
    lsum = lsum * scale + e0 + e1;
#pragma unroll
    for (int j = 0; j < 4; ++j) {
      w4[j].x = w4[j].x * scale + e0 * c4a[j].x + e1 * c4b[j].x;
      w4[j].y = w4[j].y * scale + e0 * c4a[j].y + e1 * c4b[j].y;
      w4[j].z = w4[j].z * scale + e0 * c4a[j].z + e1 * c4b[j].z;
      w4[j].w = w4[j].w * scale + e0 * c4a[j].w + e1 * c4b[j].w;
    }
    m = mn;
  }
  float* pp = part + ((size_t)b * 32 + (chunk * 4 + wid)) * 1028;
#pragma unroll
  for (int j = 0; j < 4; ++j) *(float4*)(pp + j * 256 + l * 4) = w4[j];
  if (l == 0) { pp[1024] = m; pp[1025] = lsum; }
}

// ------- K5: finish = exact alpha (from partial m/l) + combine partials -------
__launch_bounds__(256, 4)
__global__ void k_finish(const float* __restrict__ scores, const float* __restrict__ part,
                         float* __restrict__ alpha, short* __restrict__ A3) {
  __shared__ float sm[32], sl[32];
  int b = blockIdx.x, t = threadIdx.x;
  if (t < 32) {
    sm[t] = part[((size_t)b * 32 + t) * 1028 + 1024];
    sl[t] = part[((size_t)b * 32 + t) * 1028 + 1025];
  }
  __syncthreads();
  float M = -INFINITY;
#pragma unroll
  for (int i = 0; i < 32; ++i) M = fmaxf(M, sm[i]);
  float scl[32];
  float L = 0.f;
#pragma unroll
  for (int i = 0; i < 32; ++i) {
    scl[i] = __expf(sm[i] - M);
    L += sl[i] * scl[i];
  }
  float inv = 1.0f / L;
  // exact alpha from raw scores: softmax max M and denom L match the reference
  float s0 = scores[(size_t)b * 512 + t];
  float s1 = scores[(size_t)b * 512 + 256 + t];
  alpha[(size_t)b * 512 + t] = __expf(s0 - M) * inv;
  alpha[(size_t)b * 512 + 256 + t] = __expf(s1 - M) * inv;
  // combine weighted partials (h = t*4)
  float ax = 0.f, ay = 0.f, az = 0.f, aw = 0.f;
#pragma unroll
  for (int i = 0; i < 32; ++i) {
    const float4 w = *(const float4*)(part + ((size_t)b * 32 + i) * 1028 + t * 4);
    ax += scl[i] * w.x; ay += scl[i] * w.y; az += scl[i] * w.z; aw += scl[i] * w.w;
  }
  short4 o4;
  o4.x = f2bf(ax * inv); o4.y = f2bf(ay * inv); o4.z = f2bf(az * inv); o4.w = f2bf(aw * inv);
  *(short4*)(A3 + (size_t)b * 2048 + t * 4) = o4;
}

extern "C" void kernel_launch(void* const* d_in, const int* in_sizes, int n_in,
                              void* d_out, int out_size, void* d_ws, size_t ws_size,
                              hipStream_t stream) {
  const int* prev = (const int*)d_in[0];
  const float* h0 = (const float*)d_in[1];
  const float* c0 = (const float*)d_in[2];
  const float* ctx = (const float*)d_in[3];
  const unsigned char* mask = (const unsigned char*)d_in[4];
  const float* emb = (const float*)d_in[5];
  const float* W_ih = (const float*)d_in[6];
  const float* W_hh = (const float*)d_in[7];
  const float* b_ih = (const float*)d_in[8];
  const float* b_hh = (const float*)d_in[9];
  const float* W_in = (const float*)d_in[10];
  const float* W_out = (const float*)d_in[11];
  const float* W_dec = (const float*)d_in[12];
  const float* b_dec = (const float*)d_in[13];

  float* out_h1 = (float*)d_out;            // 128*1024
  float* out_c1 = out_h1 + 128 * 1024;      // 128*1024
  float* out_alpha = out_c1 + 128 * 1024;   // 128*512
  float* out_logit = out_alpha + 128 * 512; // 128*32000

  char* ws = (char*)d_ws;
  short* A1 = (short*)(ws + 0x000000);      // 128x1536 bf16 (384KB)
  float* gates = (float*)(ws + 0x060000);   // 128x4096 f32  (2MB)
  short* A3 = (short*)(ws + 0x260000);      // 128x2048 bf16 [weighted | h1] (512KB)
  float* target = (float*)(ws + 0x2E0000);  // 128x1024 f32  (512KB)
  float* scores = (float*)(ws + 0x360000);  // 128x512 f32   (256KB)
  float* part = (float*)(ws + 0x3A0000);    // 128x32x1028 f32 (16.8MB)
  short* htilde = (short*)(ws + 0x1400000); // 128x1024 bf16 (256KB)

  // 1) pack gather+h0 operand
  k_pack_a1<<<768, 256, 0, stream>>>(prev, emb, h0, A1);
  // 2) gates = [emb|h0] @ [W_ih|W_hh]^T + b_ih + b_hh   (N=4096, K=1536)
  k_gemm<128, 1, 0><<<dim3(256, 1), 256, 0, stream>>>(A1, 1536, W_ih, 512, 512, W_hh, 1024,
                                                      1536, b_ih, b_hh, gates, nullptr, 4096);
  // 3) LSTM cell -> h_1, c_1 (+ bf16 h1 into A3 second half)
  k_lstm<<<512, 256, 0, stream>>>(gates, c0, out_h1, out_c1, A3);
  // 4) target = h1 @ W_in^T (N=1024, K=1024), M-split x2
  k_gemm<64, 1, 0><<<dim3(64, 2), 256, 0, stream>>>(A3 + 1024, 2048, W_in, 1024, 1024, W_in,
                                                    1024, 1024, nullptr, nullptr, target,
                                                    nullptr, 1024);
  // 5) flash attention over ctx (read once): scores + online partials
  k_attn<<<1024, 256, 0, stream>>>(ctx, target, mask, scores, part);
  // 6) alpha + combine partials -> weighted (bf16 into A3 first half)
  k_finish<<<128, 256, 0, stream>>>(scores, part, out_alpha, A3);
  // 7) h_tilde = tanh([weighted|h1] @ W_out^T) (N=1024, K=2048), bf16 out, M-split x2
  k_gemm<64, 1, 1><<<dim3(64, 2), 256, 0, stream>>>(A3, 2048, W_out, 2048, 2048, W_out, 2048,
                                                    2048, nullptr, nullptr, nullptr, htilde,
                                                    1024);
  // 8) logit = h_tilde @ W_dec^T + b_dec (N=32000, K=1024)
  k_gemm<128, 4, 0><<<dim3(500, 1), 256, 0, stream>>>(htilde, 1024, W_dec, 1024, 1024, W_dec,
                                                      1024, 1024, b_dec, nullptr, out_logit,
                                                      nullptr, 32000);
}

// Round 5
// 158.690 us; speedup vs baseline: 1.5272x; 1.4936x over previous
//
#include <hip/hip_runtime.h>
#include <hip/hip_bf16.h>
#include <cstdint>

#define NEG_BIG (-1.0e9f)

typedef __attribute__((ext_vector_type(8))) short short8_t;
typedef __attribute__((ext_vector_type(4))) float f32x4;

typedef __attribute__((address_space(1))) const unsigned int gu32_t;
typedef __attribute__((address_space(3))) unsigned int lu32_t;

__device__ __forceinline__ short f2bf(float x) {
  union { float f; unsigned u; } v; v.f = x;
  unsigned r = v.u + 0x7fffu + ((v.u >> 16) & 1u);
  return (short)(r >> 16);
}
__device__ __forceinline__ float sigmoidf_(float x) { return 1.0f / (1.0f + __expf(-x)); }

// compiler-level barrier without the __syncthreads() vmcnt(0) drain
__device__ __forceinline__ void block_barrier() {
  asm volatile("" ::: "memory");
  __builtin_amdgcn_s_barrier();
  asm volatile("" ::: "memory");
}

// ---------------- K0: pack A1 = [emb[prev] | h0] as bf16, rows of 1536 ----------------
__global__ void k_pack_a1(const int* __restrict__ prev, const float* __restrict__ emb,
                          const float* __restrict__ h0, short* __restrict__ A1) {
  int t = blockIdx.x * 256 + threadIdx.x;
  if (t >= 128 * 1536) return;
  int b = t / 1536, k = t - b * 1536;
  float v = (k < 512) ? emb[(size_t)prev[b] * 512 + k] : h0[b * 1024 + (k - 512)];
  A1[t] = f2bf(v);
}

// ------- M-tiled bf16-MFMA GEMM with 2-phase reg-staged pipeline ------------
// C[128][N] = A(bf16)[128][Ktot] @ W(f32)[N][Ktot]^T
template <int MB, int WN, int EPI>
__launch_bounds__(256, 2)
__global__ void k_gemm(const short* __restrict__ A, int lda,
                       const float* __restrict__ Wa, int ldwa, int Ka,
                       const float* __restrict__ Wb, int ldwb, int Ktot,
                       const float* __restrict__ bias0, const float* __restrict__ bias1,
                       float* __restrict__ outF, short* __restrict__ outB, int ldo) {
  constexpr int BN = WN * 16;
  constexpr int MREP = (MB == 128) ? 2 * WN : 1;
  constexpr int AU = MB / 32;                 // short8 units per thread (A stage)
  constexpr int WLOADS = (BN * 64) / 1024;    // float4 loads per thread (W stage)
  __shared__ __align__(16) short lA[2][MB * 64];
  __shared__ __align__(16) short lW[2][BN * 64];
  const int tid = threadIdx.x;
  const int wid = tid >> 6, l = tid & 63, l15 = l & 15, khalf = l >> 4;
  const int nblk = blockIdx.x;
  const int mrow0 = blockIdx.y * MB;
  const int m_wave = (WN == 1) ? wid * (MB / 4) : 0;
  const int nb_local = (WN == 4) ? wid * 16 : 0;

  const int arow = (MB == 128) ? (tid >> 1) : (tid >> 2);
  const int apart = (MB == 128) ? (tid & 1) : (tid & 3);
  const int abase = apart * (AU * 16);
  const int aswz = (arow & 7) << 4;
  const short* Arow = A + (size_t)(mrow0 + arow) * lda + apart * (AU * 8);

  int wn_[WLOADS], wkq_[WLOADS];
#pragma unroll
  for (int j = 0; j < WLOADS; ++j) {
    int idx = j * 1024 + tid * 4;
    wn_[j] = idx >> 6;
    wkq_[j] = idx & 63;
  }

  f32x4 acc[MREP];
#pragma unroll
  for (int r = 0; r < MREP; ++r) acc[r] = (f32x4){0.f, 0.f, 0.f, 0.f};

  short8_t aR[AU];
  float4 wR[WLOADS];

  auto stage_regs = [&](int k0) {
#pragma unroll
    for (int q = 0; q < AU; ++q) aR[q] = *(const short8_t*)(Arow + k0 + q * 8);
#pragma unroll
    for (int j = 0; j < WLOADS; ++j) {
      int kg = k0 + wkq_[j];
      const float* p = (kg < Ka) ? (Wa + (size_t)(nblk * BN + wn_[j]) * ldwa + kg)
                                 : (Wb + (size_t)(nblk * BN + wn_[j]) * ldwb + (kg - Ka));
      wR[j] = *(const float4*)p;
    }
  };
  auto write_lds = [&](int buf) {
    char* drow = (char*)lA[buf] + arow * 128;
#pragma unroll
    for (int q = 0; q < AU; ++q)
      *(short8_t*)(drow + ((abase + q * 16) ^ aswz)) = aR[q];
#pragma unroll
    for (int j = 0; j < WLOADS; ++j) {
      short4 h4;
      h4.x = f2bf(wR[j].x); h4.y = f2bf(wR[j].y); h4.z = f2bf(wR[j].z); h4.w = f2bf(wR[j].w);
      *(short4*)((char*)lW[buf] + wn_[j] * 128 + ((wkq_[j] * 2) ^ ((wn_[j] & 7) << 4))) = h4;
    }
  };
  auto compute = [&](int buf) {
#pragma unroll
    for (int ks = 0; ks < 2; ++ks) {
      const int ubyte = ks * 64 + khalf * 16;
      const int nrow = nb_local + l15;
      short8_t bfrag = *(const short8_t*)((char*)lW[buf] + nrow * 128 + (ubyte ^ ((nrow & 7) << 4)));
#pragma unroll
      for (int r = 0; r < MREP; ++r) {
        const int mrow = m_wave + r * 16 + l15;
        short8_t afrag = *(const short8_t*)((char*)lA[buf] + mrow * 128 + (ubyte ^ ((mrow & 7) << 4)));
        acc[r] = __builtin_amdgcn_mfma_f32_16x16x32_bf16(afrag, bfrag, acc[r], 0, 0, 0);
      }
    }
  };

  const int NT = Ktot >> 6;
  stage_regs(0);
  write_lds(0);
  for (int t = 0; t < NT; ++t) {
    const int cur = t & 1;
    if (t + 1 < NT) stage_regs((t + 1) << 6);   // loads in flight across barrier
    __syncthreads();                            // buf[cur] ready
    compute(cur);
    if (t + 1 < NT) write_lds(cur ^ 1);
  }

  const int n = nblk * BN + nb_local + l15;
  float bias = 0.f;
  if (bias0) bias = bias0[n];
  if (bias1) bias += bias1[n];
#pragma unroll
  for (int r = 0; r < MREP; ++r) {
    int mb = mrow0 + m_wave + r * 16 + khalf * 4;
#pragma unroll
    for (int e = 0; e < 4; ++e) {
      float v = acc[r][e] + bias;
      if (EPI == 1) {
        outB[(size_t)(mb + e) * ldo + n] = f2bf(tanhf(v));
      } else {
        outF[(size_t)(mb + e) * ldo + n] = v;
      }
    }
  }
}

// ---------------- K2: LSTM elementwise ----------------
__global__ void k_lstm(const float* __restrict__ gates, const float* __restrict__ c0,
                       float* __restrict__ h1_out, float* __restrict__ c1_out,
                       short* __restrict__ A3) {
  int t = blockIdx.x * 256 + threadIdx.x;  // 131072
  int b = t >> 10, h = t & 1023;
  const float* g = gates + (size_t)b * 4096;
  float ig = sigmoidf_(g[h]);
  float fg = sigmoidf_(g[1024 + h]);
  float gg = tanhf(g[2048 + h]);
  float og = sigmoidf_(g[3072 + h]);
  float c1 = fg * c0[t] + ig * gg;
  float h1 = og * tanhf(c1);
  c1_out[t] = c1;
  h1_out[t] = h1;
  A3[(size_t)b * 2048 + 1024 + h] = f2bf(h1);  // second half of concat row
}

// ---------------- K4: flash attention, LDS-staged streaming (ctx read ONCE) -----------
// grid 1024: b = bid>>3, chunk = bid&7 (64 rows). 8 tiles of 8 rows (32KB), double-
// buffered via global_load_lds; counted vmcnt(8) keeps next tile in flight across
// raw s_barriers. Per wave: 2 rows per tile; only one row fragment (16 VGPR) live.
__launch_bounds__(256, 2)
__global__ void k_attn(const float* __restrict__ ctx, const float* __restrict__ target,
                       const unsigned char* __restrict__ mask,
                       float* __restrict__ scores, float* __restrict__ part) {
  __shared__ __align__(16) float lds[2][8 * 1024];  // 2 x 32KB
  const int b = blockIdx.x >> 3, chunk = blockIdx.x & 7;
  const int tid = threadIdx.x;
  const int wid = tid >> 6, l = tid & 63;
  const float* tg = target + (size_t)b * 1024;
  float4 t4[4], w4[4];
#pragma unroll
  for (int j = 0; j < 4; ++j) {
    t4[j] = *(const float4*)(tg + j * 256 + l * 4);
    w4[j].x = 0.f; w4[j].y = 0.f; w4[j].z = 0.f; w4[j].w = 0.f;
  }
  float m = -INFINITY, lsum = 0.f;
  const int s0 = chunk * 64;
  const float* cb = ctx + ((size_t)b * 512 + s0) * 1024;
  const unsigned char* mk = mask + (size_t)b * 512 + s0;

  auto stage = [&](int buf, int tt) {
    const char* src = (const char*)(cb + (size_t)tt * 8192);
    char* dst = (char*)&lds[buf][0];
#pragma unroll
    for (int i = 0; i < 8; ++i) {
      const int off = i * 4096 + tid * 16;  // wave-uniform base + lane*16 (linear)
      __builtin_amdgcn_global_load_lds((gu32_t*)(src + off), (lu32_t*)(dst + off), 16, 0, 0);
    }
  };

  stage(0, 0);
  int buf = 0;
  for (int t = 0; t < 8; ++t) {
    if (t < 7) {
      stage(buf ^ 1, t + 1);
      asm volatile("s_waitcnt vmcnt(8)" ::: "memory");  // tile t done; t+1 in flight
    } else {
      asm volatile("s_waitcnt vmcnt(0)" ::: "memory");
    }
    block_barrier();  // B1: tile t visible to all waves
#pragma unroll
    for (int rr = 0; rr < 2; ++rr) {
      const int r = wid * 2 + rr;
      const float* row = &lds[buf][r * 1024];
      float4 c0 = *(const float4*)(row + l * 4);
      float4 c1 = *(const float4*)(row + 256 + l * 4);
      float4 c2 = *(const float4*)(row + 512 + l * 4);
      float4 c3 = *(const float4*)(row + 768 + l * 4);
      float p = c0.x * t4[0].x + c0.y * t4[0].y + c0.z * t4[0].z + c0.w * t4[0].w +
                c1.x * t4[1].x + c1.y * t4[1].y + c1.z * t4[1].z + c1.w * t4[1].w +
                c2.x * t4[2].x + c2.y * t4[2].y + c2.z * t4[2].z + c2.w * t4[2].w +
                c3.x * t4[3].x + c3.y * t4[3].y + c3.z * t4[3].z + c3.w * t4[3].w;
#pragma unroll
      for (int off = 32; off > 0; off >>= 1) p += __shfl_xor(p, off);
      const int sg = t * 8 + r;
      if (mk[sg]) p = NEG_BIG;
      if (l == 0) scores[(size_t)b * 512 + s0 + sg] = p;
      float mn = fmaxf(m, p);
      float scale = __expf(m - mn);
      float e = __expf(p - mn);
      lsum = lsum * scale + e;
      w4[0].x = w4[0].x * scale + e * c0.x; w4[0].y = w4[0].y * scale + e * c0.y;
      w4[0].z = w4[0].z * scale + e * c0.z; w4[0].w = w4[0].w * scale + e * c0.w;
      w4[1].x = w4[1].x * scale + e * c1.x; w4[1].y = w4[1].y * scale + e * c1.y;
      w4[1].z = w4[1].z * scale + e * c1.z; w4[1].w = w4[1].w * scale + e * c1.w;
      w4[2].x = w4[2].x * scale + e * c2.x; w4[2].y = w4[2].y * scale + e * c2.y;
      w4[2].z = w4[2].z * scale + e * c2.z; w4[2].w = w4[2].w * scale + e * c2.w;
      w4[3].x = w4[3].x * scale + e * c3.x; w4[3].y = w4[3].y * scale + e * c3.y;
      w4[3].z = w4[3].z * scale + e * c3.z; w4[3].w = w4[3].w * scale + e * c3.w;
      m = mn;
    }
    block_barrier();  // B2: all waves done reading lds[buf] before overwrite
    buf ^= 1;
  }
  float* pp = part + ((size_t)b * 32 + (chunk * 4 + wid)) * 1028;
#pragma unroll
  for (int j = 0; j < 4; ++j) *(float4*)(pp + j * 256 + l * 4) = w4[j];
  if (l == 0) { pp[1024] = m; pp[1025] = lsum; }
}

// ------- K5: finish = exact alpha (from partial m/l) + combine partials -------
__launch_bounds__(256, 4)
__global__ void k_finish(const float* __restrict__ scores, const float* __restrict__ part,
                         float* __restrict__ alpha, short* __restrict__ A3) {
  __shared__ float sm[32], sl[32];
  int b = blockIdx.x, t = threadIdx.x;
  if (t < 32) {
    sm[t] = part[((size_t)b * 32 + t) * 1028 + 1024];
    sl[t] = part[((size_t)b * 32 + t) * 1028 + 1025];
  }
  __syncthreads();
  float M = -INFINITY;
#pragma unroll
  for (int i = 0; i < 32; ++i) M = fmaxf(M, sm[i]);
  float scl[32];
  float L = 0.f;
#pragma unroll
  for (int i = 0; i < 32; ++i) {
    scl[i] = __expf(sm[i] - M);
    L += sl[i] * scl[i];
  }
  float inv = 1.0f / L;
  float s0 = scores[(size_t)b * 512 + t];
  float s1 = scores[(size_t)b * 512 + 256 + t];
  alpha[(size_t)b * 512 + t] = __expf(s0 - M) * inv;
  alpha[(size_t)b * 512 + 256 + t] = __expf(s1 - M) * inv;
  float ax = 0.f, ay = 0.f, az = 0.f, aw = 0.f;
#pragma unroll
  for (int i = 0; i < 32; ++i) {
    const float4 w = *(const float4*)(part + ((size_t)b * 32 + i) * 1028 + t * 4);
    ax += scl[i] * w.x; ay += scl[i] * w.y; az += scl[i] * w.z; aw += scl[i] * w.w;
  }
  short4 o4;
  o4.x = f2bf(ax * inv); o4.y = f2bf(ay * inv); o4.z = f2bf(az * inv); o4.w = f2bf(aw * inv);
  *(short4*)(A3 + (size_t)b * 2048 + t * 4) = o4;
}

extern "C" void kernel_launch(void* const* d_in, const int* in_sizes, int n_in,
                              void* d_out, int out_size, void* d_ws, size_t ws_size,
                              hipStream_t stream) {
  const int* prev = (const int*)d_in[0];
  const float* h0 = (const float*)d_in[1];
  const float* c0 = (const float*)d_in[2];
  const float* ctx = (const float*)d_in[3];
  const unsigned char* mask = (const unsigned char*)d_in[4];
  const float* emb = (const float*)d_in[5];
  const float* W_ih = (const float*)d_in[6];
  const float* W_hh = (const float*)d_in[7];
  const float* b_ih = (const float*)d_in[8];
  const float* b_hh = (const float*)d_in[9];
  const float* W_in = (const float*)d_in[10];
  const float* W_out = (const float*)d_in[11];
  const float* W_dec = (const float*)d_in[12];
  const float* b_dec = (const float*)d_in[13];

  float* out_h1 = (float*)d_out;            // 128*1024
  float* out_c1 = out_h1 + 128 * 1024;      // 128*1024
  float* out_alpha = out_c1 + 128 * 1024;   // 128*512
  float* out_logit = out_alpha + 128 * 512; // 128*32000

  char* ws = (char*)d_ws;
  short* A1 = (short*)(ws + 0x000000);      // 128x1536 bf16 (384KB)
  float* gates = (float*)(ws + 0x060000);   // 128x4096 f32  (2MB)
  short* A3 = (short*)(ws + 0x260000);      // 128x2048 bf16 [weighted | h1] (512KB)
  float* target = (float*)(ws + 0x2E0000);  // 128x1024 f32  (512KB)
  float* scores = (float*)(ws + 0x360000);  // 128x512 f32   (256KB)
  float* part = (float*)(ws + 0x3A0000);    // 128x32x1028 f32 (16.8MB)
  short* htilde = (short*)(ws + 0x1400000); // 128x1024 bf16 (256KB)

  // 1) pack gather+h0 operand
  k_pack_a1<<<768, 256, 0, stream>>>(prev, emb, h0, A1);
  // 2) gates = [emb|h0] @ [W_ih|W_hh]^T + b_ih + b_hh   (N=4096, K=1536)
  k_gemm<128, 1, 0><<<dim3(256, 1), 256, 0, stream>>>(A1, 1536, W_ih, 512, 512, W_hh, 1024,
                                                      1536, b_ih, b_hh, gates, nullptr, 4096);
  // 3) LSTM cell -> h_1, c_1 (+ bf16 h1 into A3 second half)
  k_lstm<<<512, 256, 0, stream>>>(gates, c0, out_h1, out_c1, A3);
  // 4) target = h1 @ W_in^T (N=1024, K=1024), M-split x2
  k_gemm<64, 1, 0><<<dim3(64, 2), 256, 0, stream>>>(A3 + 1024, 2048, W_in, 1024, 1024, W_in,
                                                    1024, 1024, nullptr, nullptr, target,
                                                    nullptr, 1024);
  // 5) flash attention over ctx (read once): scores + online partials
  k_attn<<<1024, 256, 0, stream>>>(ctx, target, mask, scores, part);
  // 6) alpha + combine partials -> weighted (bf16 into A3 first half)
  k_finish<<<128, 256, 0, stream>>>(scores, part, out_alpha, A3);
  // 7) h_tilde = tanh([weighted|h1] @ W_out^T) (N=1024, K=2048), bf16 out, M-split x2
  k_gemm<64, 1, 1><<<dim3(64, 2), 256, 0, stream>>>(A3, 2048, W_out, 2048, 2048, W_out, 2048,
                                                    2048, nullptr, nullptr, nullptr, htilde,
                                                    1024);
  // 8) logit = h_tilde @ W_dec^T + b_dec (N=32000, K=1024)
  k_gemm<128, 4, 0><<<dim3(500, 1), 256, 0, stream>>>(htilde, 1024, W_dec, 1024, 1024, W_dec,
                                                      1024, 1024, b_dec, nullptr, out_logit,
                                                      nullptr, 32000);
}

// Round 6
// 149.200 us; speedup vs baseline: 1.6243x; 1.0636x over previous
//
#include <hip/hip_runtime.h>
#include <hip/hip_bf16.h>
#include <cstdint>

#define NEG_BIG (-1.0e9f)

typedef __attribute__((ext_vector_type(8))) short short8_t;
typedef __attribute__((ext_vector_type(4))) float f32x4;

typedef __attribute__((address_space(1))) const unsigned int gu32_t;
typedef __attribute__((address_space(3))) unsigned int lu32_t;

__device__ __forceinline__ short f2bf(float x) {
  union { float f; unsigned u; } v; v.f = x;
  unsigned r = v.u + 0x7fffu + ((v.u >> 16) & 1u);
  return (short)(r >> 16);
}
__device__ __forceinline__ float sigmoidf_(float x) { return 1.0f / (1.0f + __expf(-x)); }

// barrier with LDS-visibility only: vmcnt stays un-drained (loads stay in flight)
__device__ __forceinline__ void lds_barrier() {
  asm volatile("s_waitcnt lgkmcnt(0)\n\ts_barrier" ::: "memory");
}
// plain barrier (no waitcnt at all) for k_attn (vmcnt handled explicitly there)
__device__ __forceinline__ void block_barrier() {
  asm volatile("" ::: "memory");
  __builtin_amdgcn_s_barrier();
  asm volatile("" ::: "memory");
}

// ====== K1: fused [emb-gather | h0] GEMM + LSTM cell ======
// grid (64, 2): hb = 16-h block, mrow0 = 64-row M split. BN=64 = 4 gates x 16 h.
// Epilogue: gate accs -> LDS transpose -> elementwise LSTM -> h1,c1 (+bf16 h1 into A3).
__launch_bounds__(256, 2)
__global__ void k_gates(const int* __restrict__ prev, const float* __restrict__ emb,
                        const float* __restrict__ h0,
                        const float* __restrict__ W_ih, const float* __restrict__ W_hh,
                        const float* __restrict__ b_ih, const float* __restrict__ b_hh,
                        const float* __restrict__ c0,
                        float* __restrict__ h1_out, float* __restrict__ c1_out,
                        short* __restrict__ A3) {
  __shared__ __align__(16) short lA[2][64 * 64];
  __shared__ __align__(16) short lW[2][64 * 64];
  const int tid = threadIdx.x;
  const int wid = tid >> 6, l = tid & 63, l15 = l & 15, khalf = l >> 4;
  const int hb = blockIdx.x;
  const int mrow0 = blockIdx.y * 64;

  // A staging: 4 thr/row, 16 f32 each
  const int arow = tid >> 2;
  const int apart = tid & 3;
  const int aswz = (arow & 7) << 4;
  const int bA = mrow0 + arow;
  const int pv = prev[bA];
  const float* embrow = emb + (size_t)pv * 512 + apart * 16;
  const float* h0row = h0 + (size_t)bA * 1024 + apart * 16;

  // W staging: 4 float4/thread; tile row n -> W row (n>>4)*1024 + hb*16 + (n&15)
  int wrow_[4], wkq_[4];
  const float* wih_[4];
  const float* whh_[4];
#pragma unroll
  for (int j = 0; j < 4; ++j) {
    int idx = j * 1024 + tid * 4;
    int n = idx >> 6;
    wkq_[j] = idx & 63;
    wrow_[j] = n;
    int grow = (n >> 4) * 1024 + hb * 16 + (n & 15);
    wih_[j] = W_ih + (size_t)grow * 512;
    whh_[j] = W_hh + (size_t)grow * 1024;
  }

  f32x4 acc[4];
#pragma unroll
  for (int r = 0; r < 4; ++r) acc[r] = (f32x4){0.f, 0.f, 0.f, 0.f};

  float4 aF[4], wR[4];
  auto stage_regs = [&](int k0) {
    const float* asrc = (k0 < 512) ? (embrow + k0) : (h0row + (k0 - 512));
#pragma unroll
    for (int q = 0; q < 4; ++q) aF[q] = *(const float4*)(asrc + q * 4);
#pragma unroll
    for (int j = 0; j < 4; ++j) {
      int kg = k0 + wkq_[j];
      wR[j] = (kg < 512) ? *(const float4*)(wih_[j] + kg)
                         : *(const float4*)(whh_[j] + (kg - 512));
    }
  };
  auto write_lds = [&](int buf) {
    char* drow = (char*)lA[buf] + arow * 128;
#pragma unroll
    for (int q = 0; q < 2; ++q) {
      short8_t s;
      s[0] = f2bf(aF[2 * q].x); s[1] = f2bf(aF[2 * q].y);
      s[2] = f2bf(aF[2 * q].z); s[3] = f2bf(aF[2 * q].w);
      s[4] = f2bf(aF[2 * q + 1].x); s[5] = f2bf(aF[2 * q + 1].y);
      s[6] = f2bf(aF[2 * q + 1].z); s[7] = f2bf(aF[2 * q + 1].w);
      *(short8_t*)(drow + ((apart * 32 + q * 16) ^ aswz)) = s;
    }
#pragma unroll
    for (int j = 0; j < 4; ++j) {
      short4 h4;
      h4.x = f2bf(wR[j].x); h4.y = f2bf(wR[j].y); h4.z = f2bf(wR[j].z); h4.w = f2bf(wR[j].w);
      *(short4*)((char*)lW[buf] + wrow_[j] * 128 + ((wkq_[j] * 2) ^ ((wrow_[j] & 7) << 4))) = h4;
    }
  };
  auto compute = [&](int buf) {
#pragma unroll
    for (int ks = 0; ks < 2; ++ks) {
      const int ubyte = ks * 64 + khalf * 16;
      const int nrow = wid * 16 + l15;
      short8_t bfrag = *(const short8_t*)((char*)lW[buf] + nrow * 128 + (ubyte ^ ((nrow & 7) << 4)));
#pragma unroll
      for (int r = 0; r < 4; ++r) {
        const int mrow = r * 16 + l15;
        short8_t afrag = *(const short8_t*)((char*)lA[buf] + mrow * 128 + (ubyte ^ ((mrow & 7) << 4)));
        acc[r] = __builtin_amdgcn_mfma_f32_16x16x32_bf16(afrag, bfrag, acc[r], 0, 0, 0);
      }
    }
  };

  stage_regs(0);
  write_lds(0);
  for (int t = 0; t < 24; ++t) {
    const int cur = t & 1;
    if (t + 1 < 24) stage_regs((t + 1) << 6);  // stays in flight across barrier
    lds_barrier();
    compute(cur);
    if (t + 1 < 24) write_lds(cur ^ 1);
  }

  // ---- LSTM epilogue: wave w holds gate w for (m = r*16+khalf*4+e, h = l15) ----
  lds_barrier();  // all waves done reading lA/lW
  float* gbuf = (float*)&lA[0][0];  // [4 gates][64 m][16 h] = 16 KB (aliases lA)
#pragma unroll
  for (int r = 0; r < 4; ++r)
#pragma unroll
    for (int e = 0; e < 4; ++e)
      gbuf[wid * 1024 + (r * 16 + khalf * 4 + e) * 16 + l15] = acc[r][e];
  __syncthreads();
#pragma unroll
  for (int q = 0; q < 4; ++q) {
    int idx = q * 256 + tid;
    int hloc = idx & 15, mloc = idx >> 4;
    int b = mrow0 + mloc;
    int hh = hb * 16 + hloc;
    float iv = gbuf[0 + mloc * 16 + hloc] + b_ih[hh] + b_hh[hh];
    float fv = gbuf[1024 + mloc * 16 + hloc] + b_ih[1024 + hh] + b_hh[1024 + hh];
    float gv = gbuf[2048 + mloc * 16 + hloc] + b_ih[2048 + hh] + b_hh[2048 + hh];
    float ov = gbuf[3072 + mloc * 16 + hloc] + b_ih[3072 + hh] + b_hh[3072 + hh];
    float c1 = sigmoidf_(fv) * c0[(size_t)b * 1024 + hh] + sigmoidf_(iv) * tanhf(gv);
    float h1 = sigmoidf_(ov) * tanhf(c1);
    c1_out[(size_t)b * 1024 + hh] = c1;
    h1_out[(size_t)b * 1024 + hh] = h1;
    A3[(size_t)b * 2048 + 1024 + hh] = f2bf(h1);
  }
}

// ------- M-tiled bf16-MFMA GEMM, 2-phase reg-staged pipeline (vmcnt un-drained) -------
template <int MB, int WN, int EPI>
__launch_bounds__(256, 2)
__global__ void k_gemm(const short* __restrict__ A, int lda,
                       const float* __restrict__ Wa, int ldwa, int Ka,
                       const float* __restrict__ Wb, int ldwb, int Ktot,
                       const float* __restrict__ bias0, const float* __restrict__ bias1,
                       float* __restrict__ outF, short* __restrict__ outB, int ldo) {
  constexpr int BN = WN * 16;
  constexpr int MREP = (MB == 128) ? 2 * WN : 1;
  constexpr int AU = MB / 32;
  constexpr int WLOADS = (BN * 64) / 1024;
  __shared__ __align__(16) short lA[2][MB * 64];
  __shared__ __align__(16) short lW[2][BN * 64];
  const int tid = threadIdx.x;
  const int wid = tid >> 6, l = tid & 63, l15 = l & 15, khalf = l >> 4;
  const int nblk = blockIdx.x;
  const int mrow0 = blockIdx.y * MB;
  const int m_wave = (WN == 1) ? wid * (MB / 4) : 0;
  const int nb_local = (WN == 4) ? wid * 16 : 0;

  const int arow = (MB == 128) ? (tid >> 1) : (tid >> 2);
  const int apart = (MB == 128) ? (tid & 1) : (tid & 3);
  const int abase = apart * (AU * 16);
  const int aswz = (arow & 7) << 4;
  const short* Arow = A + (size_t)(mrow0 + arow) * lda + apart * (AU * 8);

  int wn_[WLOADS], wkq_[WLOADS];
#pragma unroll
  for (int j = 0; j < WLOADS; ++j) {
    int idx = j * 1024 + tid * 4;
    wn_[j] = idx >> 6;
    wkq_[j] = idx & 63;
  }

  f32x4 acc[MREP];
#pragma unroll
  for (int r = 0; r < MREP; ++r) acc[r] = (f32x4){0.f, 0.f, 0.f, 0.f};

  short8_t aR[AU];
  float4 wR[WLOADS];

  auto stage_regs = [&](int k0) {
#pragma unroll
    for (int q = 0; q < AU; ++q) aR[q] = *(const short8_t*)(Arow + k0 + q * 8);
#pragma unroll
    for (int j = 0; j < WLOADS; ++j) {
      int kg = k0 + wkq_[j];
      const float* p = (kg < Ka) ? (Wa + (size_t)(nblk * BN + wn_[j]) * ldwa + kg)
                                 : (Wb + (size_t)(nblk * BN + wn_[j]) * ldwb + (kg - Ka));
      wR[j] = *(const float4*)p;
    }
  };
  auto write_lds = [&](int buf) {
    char* drow = (char*)lA[buf] + arow * 128;
#pragma unroll
    for (int q = 0; q < AU; ++q)
      *(short8_t*)(drow + ((abase + q * 16) ^ aswz)) = aR[q];
#pragma unroll
    for (int j = 0; j < WLOADS; ++j) {
      short4 h4;
      h4.x = f2bf(wR[j].x); h4.y = f2bf(wR[j].y); h4.z = f2bf(wR[j].z); h4.w = f2bf(wR[j].w);
      *(short4*)((char*)lW[buf] + wn_[j] * 128 + ((wkq_[j] * 2) ^ ((wn_[j] & 7) << 4))) = h4;
    }
  };
  auto compute = [&](int buf) {
#pragma unroll
    for (int ks = 0; ks < 2; ++ks) {
      const int ubyte = ks * 64 + khalf * 16;
      const int nrow = nb_local + l15;
      short8_t bfrag = *(const short8_t*)((char*)lW[buf] + nrow * 128 + (ubyte ^ ((nrow & 7) << 4)));
#pragma unroll
      for (int r = 0; r < MREP; ++r) {
        const int mrow = m_wave + r * 16 + l15;
        short8_t afrag = *(const short8_t*)((char*)lA[buf] + mrow * 128 + (ubyte ^ ((mrow & 7) << 4)));
        acc[r] = __builtin_amdgcn_mfma_f32_16x16x32_bf16(afrag, bfrag, acc[r], 0, 0, 0);
      }
    }
  };

  const int NT = Ktot >> 6;
  stage_regs(0);
  write_lds(0);
  for (int t = 0; t < NT; ++t) {
    const int cur = t & 1;
    if (t + 1 < NT) stage_regs((t + 1) << 6);  // loads in flight across barrier
    lds_barrier();                             // LDS visibility only; vmcnt free
    compute(cur);
    if (t + 1 < NT) write_lds(cur ^ 1);
  }

  const int n = nblk * BN + nb_local + l15;
  float bias = 0.f;
  if (bias0) bias = bias0[n];
  if (bias1) bias += bias1[n];
#pragma unroll
  for (int r = 0; r < MREP; ++r) {
    int mb = mrow0 + m_wave + r * 16 + khalf * 4;
#pragma unroll
    for (int e = 0; e < 4; ++e) {
      float v = acc[r][e] + bias;
      if (EPI == 1) {
        outB[(size_t)(mb + e) * ldo + n] = f2bf(tanhf(v));
      } else {
        outF[(size_t)(mb + e) * ldo + n] = v;
      }
    }
  }
}

// ---------------- K4: flash attention, LDS-staged streaming (ctx read ONCE) -----------
// grid 512: b = bid>>2, chunk = bid&3 (128 rows). 16 tiles of 8 rows (32KB), double-
// buffered via global_load_lds; counted vmcnt(8) keeps next tile in flight.
__launch_bounds__(256, 2)
__global__ void k_attn(const float* __restrict__ ctx, const float* __restrict__ target,
                       const unsigned char* __restrict__ mask,
                       float* __restrict__ scores, float* __restrict__ part) {
  __shared__ __align__(16) float lds[2][8 * 1024];  // 2 x 32KB
  const int b = blockIdx.x >> 2, chunk = blockIdx.x & 3;
  const int tid = threadIdx.x;
  const int wid = tid >> 6, l = tid & 63;
  const float* tg = target + (size_t)b * 1024;
  float4 t4[4], w4[4];
#pragma unroll
  for (int j = 0; j < 4; ++j) {
    t4[j] = *(const float4*)(tg + j * 256 + l * 4);
    w4[j].x = 0.f; w4[j].y = 0.f; w4[j].z = 0.f; w4[j].w = 0.f;
  }
  float m = -INFINITY, lsum = 0.f;
  const int s0 = chunk * 128;
  const float* cb = ctx + ((size_t)b * 512 + s0) * 1024;
  const unsigned char* mk = mask + (size_t)b * 512 + s0;

  auto stage = [&](int buf, int tt) {
    const char* src = (const char*)(cb + (size_t)tt * 8192);
    char* dst = (char*)&lds[buf][0];
#pragma unroll
    for (int i = 0; i < 8; ++i) {
      const int off = i * 4096 + tid * 16;
      __builtin_amdgcn_global_load_lds((gu32_t*)(src + off), (lu32_t*)(dst + off), 16, 0, 0);
    }
  };

  stage(0, 0);
  int buf = 0;
  for (int t = 0; t < 16; ++t) {
    if (t < 15) {
      stage(buf ^ 1, t + 1);
      asm volatile("s_waitcnt vmcnt(8)" ::: "memory");  // tile t done; t+1 in flight
    } else {
      asm volatile("s_waitcnt vmcnt(0)" ::: "memory");
    }
    block_barrier();  // B1: tile t visible to all waves
#pragma unroll
    for (int rr = 0; rr < 2; ++rr) {
      const int r = wid * 2 + rr;
      const float* row = &lds[buf][r * 1024];
      float4 c0 = *(const float4*)(row + l * 4);
      float4 c1 = *(const float4*)(row + 256 + l * 4);
      float4 c2 = *(const float4*)(row + 512 + l * 4);
      float4 c3 = *(const float4*)(row + 768 + l * 4);
      float p = c0.x * t4[0].x + c0.y * t4[0].y + c0.z * t4[0].z + c0.w * t4[0].w +
                c1.x * t4[1].x + c1.y * t4[1].y + c1.z * t4[1].z + c1.w * t4[1].w +
                c2.x * t4[2].x + c2.y * t4[2].y + c2.z * t4[2].z + c2.w * t4[2].w +
                c3.x * t4[3].x + c3.y * t4[3].y + c3.z * t4[3].z + c3.w * t4[3].w;
#pragma unroll
      for (int off = 32; off > 0; off >>= 1) p += __shfl_xor(p, off);
      const int sg = t * 8 + r;
      if (mk[sg]) p = NEG_BIG;
      if (l == 0) scores[(size_t)b * 512 + s0 + sg] = p;
      float mn = fmaxf(m, p);
      float scale = __expf(m - mn);
      float e = __expf(p - mn);
      lsum = lsum * scale + e;
      w4[0].x = w4[0].x * scale + e * c0.x; w4[0].y = w4[0].y * scale + e * c0.y;
      w4[0].z = w4[0].z * scale + e * c0.z; w4[0].w = w4[0].w * scale + e * c0.w;
      w4[1].x = w4[1].x * scale + e * c1.x; w4[1].y = w4[1].y * scale + e * c1.y;
      w4[1].z = w4[1].z * scale + e * c1.z; w4[1].w = w4[1].w * scale + e * c1.w;
      w4[2].x = w4[2].x * scale + e * c2.x; w4[2].y = w4[2].y * scale + e * c2.y;
      w4[2].z = w4[2].z * scale + e * c2.z; w4[2].w = w4[2].w * scale + e * c2.w;
      w4[3].x = w4[3].x * scale + e * c3.x; w4[3].y = w4[3].y * scale + e * c3.y;
      w4[3].z = w4[3].z * scale + e * c3.z; w4[3].w = w4[3].w * scale + e * c3.w;
      m = mn;
    }
    block_barrier();  // B2: all waves done reading lds[buf] before overwrite
    buf ^= 1;
  }
  float* pp = part + ((size_t)b * 16 + (chunk * 4 + wid)) * 1028;
#pragma unroll
  for (int j = 0; j < 4; ++j) *(float4*)(pp + j * 256 + l * 4) = w4[j];
  if (l == 0) { pp[1024] = m; pp[1025] = lsum; }
}

// ------- K5: finish = exact alpha (from partial m/l) + combine partials -------
__launch_bounds__(256, 4)
__global__ void k_finish(const float* __restrict__ scores, const float* __restrict__ part,
                         float* __restrict__ alpha, short* __restrict__ A3) {
  __shared__ float sm[16], sl[16];
  int b = blockIdx.x, t = threadIdx.x;
  if (t < 16) {
    sm[t] = part[((size_t)b * 16 + t) * 1028 + 1024];
    sl[t] = part[((size_t)b * 16 + t) * 1028 + 1025];
  }
  __syncthreads();
  float M = -INFINITY;
#pragma unroll
  for (int i = 0; i < 16; ++i) M = fmaxf(M, sm[i]);
  float scl[16];
  float L = 0.f;
#pragma unroll
  for (int i = 0; i < 16; ++i) {
    scl[i] = __expf(sm[i] - M);
    L += sl[i] * scl[i];
  }
  float inv = 1.0f / L;
  float s0 = scores[(size_t)b * 512 + t];
  float s1 = scores[(size_t)b * 512 + 256 + t];
  alpha[(size_t)b * 512 + t] = __expf(s0 - M) * inv;
  alpha[(size_t)b * 512 + 256 + t] = __expf(s1 - M) * inv;
  float ax = 0.f, ay = 0.f, az = 0.f, aw = 0.f;
#pragma unroll
  for (int i = 0; i < 16; ++i) {
    const float4 w = *(const float4*)(part + ((size_t)b * 16 + i) * 1028 + t * 4);
    ax += scl[i] * w.x; ay += scl[i] * w.y; az += scl[i] * w.z; aw += scl[i] * w.w;
  }
  short4 o4;
  o4.x = f2bf(ax * inv); o4.y = f2bf(ay * inv); o4.z = f2bf(az * inv); o4.w = f2bf(aw * inv);
  *(short4*)(A3 + (size_t)b * 2048 + t * 4) = o4;
}

extern "C" void kernel_launch(void* const* d_in, const int* in_sizes, int n_in,
                              void* d_out, int out_size, void* d_ws, size_t ws_size,
                              hipStream_t stream) {
  const int* prev = (const int*)d_in[0];
  const float* h0 = (const float*)d_in[1];
  const float* c0 = (const float*)d_in[2];
  const float* ctx = (const float*)d_in[3];
  const unsigned char* mask = (const unsigned char*)d_in[4];
  const float* emb = (const float*)d_in[5];
  const float* W_ih = (const float*)d_in[6];
  const float* W_hh = (const float*)d_in[7];
  const float* b_ih = (const float*)d_in[8];
  const float* b_hh = (const float*)d_in[9];
  const float* W_in = (const float*)d_in[10];
  const float* W_out = (const float*)d_in[11];
  const float* W_dec = (const float*)d_in[12];
  const float* b_dec = (const float*)d_in[13];

  float* out_h1 = (float*)d_out;            // 128*1024
  float* out_c1 = out_h1 + 128 * 1024;      // 128*1024
  float* out_alpha = out_c1 + 128 * 1024;   // 128*512
  float* out_logit = out_alpha + 128 * 512; // 128*32000

  char* ws = (char*)d_ws;
  short* A3 = (short*)(ws + 0x000000);      // 128x2048 bf16 [weighted | h1] (512KB)
  float* target = (float*)(ws + 0x100000);  // 128x1024 f32 (512KB)
  float* scores = (float*)(ws + 0x200000);  // 128x512 f32 (256KB)
  float* part = (float*)(ws + 0x300000);    // 128x16x1028 f32 (8.42MB)
  short* htilde = (short*)(ws + 0xD00000);  // 128x1024 bf16 (256KB)

  // 1) fused gather + gates GEMM + LSTM -> h1, c1, A3[:,1024:]
  k_gates<<<dim3(64, 2), 256, 0, stream>>>(prev, emb, h0, W_ih, W_hh, b_ih, b_hh, c0,
                                           out_h1, out_c1, A3);
  // 2) target = h1 @ W_in^T (N=1024, K=1024), M-split x2
  k_gemm<64, 1, 0><<<dim3(64, 2), 256, 0, stream>>>(A3 + 1024, 2048, W_in, 1024, 1024, W_in,
                                                    1024, 1024, nullptr, nullptr, target,
                                                    nullptr, 1024);
  // 3) flash attention over ctx (read once): scores + online partials
  k_attn<<<512, 256, 0, stream>>>(ctx, target, mask, scores, part);
  // 4) alpha + combine partials -> weighted (bf16 into A3 first half)
  k_finish<<<128, 256, 0, stream>>>(scores, part, out_alpha, A3);
  // 5) h_tilde = tanh([weighted|h1] @ W_out^T) (N=1024, K=2048), bf16 out, M-split x2
  k_gemm<64, 1, 1><<<dim3(64, 2), 256, 0, stream>>>(A3, 2048, W_out, 2048, 2048, W_out, 2048,
                                                    2048, nullptr, nullptr, nullptr, htilde,
                                                    1024);
  // 6) logit = h_tilde @ W_dec^T + b_dec (N=32000, K=1024)
  k_gemm<128, 4, 0><<<dim3(500, 1), 256, 0, stream>>>(htilde, 1024, W_dec, 1024, 1024, W_dec,
                                                      1024, 1024, b_dec, nullptr, out_logit,
                                                      nullptr, 32000);
}

// Round 7
// 134.299 us; speedup vs baseline: 1.8046x; 1.1110x over previous
//
#include <hip/hip_runtime.h>
#include <hip/hip_bf16.h>
#include <cstdint>

#define NEG_BIG (-1.0e9f)

typedef __attribute__((ext_vector_type(8))) short short8_t;
typedef __attribute__((ext_vector_type(4))) float f32x4;

typedef __attribute__((address_space(1))) const unsigned int gu32_t;
typedef __attribute__((address_space(3))) unsigned int lu32_t;

__device__ __forceinline__ short f2bf(float x) {
  union { float f; unsigned u; } v; v.f = x;
  unsigned r = v.u + 0x7fffu + ((v.u >> 16) & 1u);
  return (short)(r >> 16);
}
__device__ __forceinline__ float sigmoidf_(float x) { return 1.0f / (1.0f + __expf(-x)); }

// barrier with LDS-visibility only: vmcnt stays un-drained (loads stay in flight)
__device__ __forceinline__ void lds_barrier() {
  asm volatile("s_waitcnt lgkmcnt(0)\n\ts_barrier" ::: "memory");
}
// plain barrier (no waitcnt) for k_attn (vmcnt handled explicitly there)
__device__ __forceinline__ void block_barrier() {
  asm volatile("" ::: "memory");
  __builtin_amdgcn_s_barrier();
  asm volatile("" ::: "memory");
}

// ---------------- K0: pack A1 = [emb[prev] | h0] as bf16, rows of 1536 ----------------
__global__ void k_pack_a1(const int* __restrict__ prev, const float* __restrict__ emb,
                          const float* __restrict__ h0, short* __restrict__ A1) {
  int t = blockIdx.x * 256 + threadIdx.x;
  if (t >= 128 * 1536) return;
  int b = t / 1536, k = t - b * 1536;
  float v = (k < 512) ? emb[(size_t)prev[b] * 512 + k] : h0[b * 1024 + (k - 512)];
  A1[t] = f2bf(v);
}

// ------- M-tiled bf16-MFMA GEMM, 2-phase reg-staged pipeline, optional split-K -------
// C[128][N] (or partial) = A(bf16)[128][K] @ W(f32)[N][K]^T
// blockIdx.z = K-chunk: offsets A,Wa by z*kstride cols and outF by z*pstride elems.
template <int MB, int WN, int EPI>
__launch_bounds__(256, 2)
__global__ void k_gemm(const short* __restrict__ A, int lda,
                       const float* __restrict__ Wa, int ldwa, int Ka,
                       const float* __restrict__ Wb, int ldwb, int Ktot,
                       const float* __restrict__ bias0, const float* __restrict__ bias1,
                       float* __restrict__ outF, short* __restrict__ outB, int ldo,
                       int kstride, size_t pstride) {
  constexpr int BN = WN * 16;
  constexpr int MREP = (MB == 128) ? 2 * WN : 1;
  constexpr int AU = MB / 32;
  constexpr int WLOADS = (BN * 64) / 1024;
  __shared__ __align__(16) short lA[2][MB * 64];
  __shared__ __align__(16) short lW[2][BN * 64];
  const int kc = blockIdx.z;
  A += (size_t)kc * kstride;
  Wa += (size_t)kc * kstride;
  if (outF) outF += (size_t)kc * pstride;
  const int tid = threadIdx.x;
  const int wid = tid >> 6, l = tid & 63, l15 = l & 15, khalf = l >> 4;
  const int nblk = blockIdx.x;
  const int mrow0 = blockIdx.y * MB;
  const int m_wave = (WN == 1) ? wid * (MB / 4) : 0;
  const int nb_local = (WN == 4) ? wid * 16 : 0;

  const int arow = (MB == 128) ? (tid >> 1) : (tid >> 2);
  const int apart = (MB == 128) ? (tid & 1) : (tid & 3);
  const int abase = apart * (AU * 16);
  const int aswz = (arow & 7) << 4;
  const short* Arow = A + (size_t)(mrow0 + arow) * lda + apart * (AU * 8);

  int wn_[WLOADS], wkq_[WLOADS];
#pragma unroll
  for (int j = 0; j < WLOADS; ++j) {
    int idx = j * 1024 + tid * 4;
    wn_[j] = idx >> 6;
    wkq_[j] = idx & 63;
  }

  f32x4 acc[MREP];
#pragma unroll
  for (int r = 0; r < MREP; ++r) acc[r] = (f32x4){0.f, 0.f, 0.f, 0.f};

  short8_t aR[AU];
  float4 wR[WLOADS];

  auto stage_regs = [&](int k0) {
#pragma unroll
    for (int q = 0; q < AU; ++q) aR[q] = *(const short8_t*)(Arow + k0 + q * 8);
#pragma unroll
    for (int j = 0; j < WLOADS; ++j) {
      int kg = k0 + wkq_[j];
      const float* p = (kg < Ka) ? (Wa + (size_t)(nblk * BN + wn_[j]) * ldwa + kg)
                                 : (Wb + (size_t)(nblk * BN + wn_[j]) * ldwb + (kg - Ka));
      wR[j] = *(const float4*)p;
    }
  };
  auto write_lds = [&](int buf) {
    char* drow = (char*)lA[buf] + arow * 128;
#pragma unroll
    for (int q = 0; q < AU; ++q)
      *(short8_t*)(drow + ((abase + q * 16) ^ aswz)) = aR[q];
#pragma unroll
    for (int j = 0; j < WLOADS; ++j) {
      short4 h4;
      h4.x = f2bf(wR[j].x); h4.y = f2bf(wR[j].y); h4.z = f2bf(wR[j].z); h4.w = f2bf(wR[j].w);
      *(short4*)((char*)lW[buf] + wn_[j] * 128 + ((wkq_[j] * 2) ^ ((wn_[j] & 7) << 4))) = h4;
    }
  };
  auto compute = [&](int buf) {
#pragma unroll
    for (int ks = 0; ks < 2; ++ks) {
      const int ubyte = ks * 64 + khalf * 16;
      const int nrow = nb_local + l15;
      short8_t bfrag = *(const short8_t*)((char*)lW[buf] + nrow * 128 + (ubyte ^ ((nrow & 7) << 4)));
#pragma unroll
      for (int r = 0; r < MREP; ++r) {
        const int mrow = m_wave + r * 16 + l15;
        short8_t afrag = *(const short8_t*)((char*)lA[buf] + mrow * 128 + (ubyte ^ ((mrow & 7) << 4)));
        acc[r] = __builtin_amdgcn_mfma_f32_16x16x32_bf16(afrag, bfrag, acc[r], 0, 0, 0);
      }
    }
  };

  const int NT = Ktot >> 6;
  stage_regs(0);
  write_lds(0);
  for (int t = 0; t < NT; ++t) {
    const int cur = t & 1;
    if (t + 1 < NT) stage_regs((t + 1) << 6);  // loads in flight across barrier
    lds_barrier();                             // LDS visibility only; vmcnt free
    compute(cur);
    if (t + 1 < NT) write_lds(cur ^ 1);
  }

  const int n = nblk * BN + nb_local + l15;
  float bias = 0.f;
  if (bias0) bias = bias0[n];
  if (bias1) bias += bias1[n];
#pragma unroll
  for (int r = 0; r < MREP; ++r) {
    int mb = mrow0 + m_wave + r * 16 + khalf * 4;
#pragma unroll
    for (int e = 0; e < 4; ++e) {
      float v = acc[r][e] + bias;
      if (EPI == 1) {
        outB[(size_t)(mb + e) * ldo + n] = f2bf(tanhf(v));
      } else {
        outF[(size_t)(mb + e) * ldo + n] = v;
      }
    }
  }
}

// ---------------- K2: LSTM elementwise ----------------
__global__ void k_lstm(const float* __restrict__ gates, const float* __restrict__ c0,
                       float* __restrict__ h1_out, float* __restrict__ c1_out,
                       short* __restrict__ A3) {
  int t = blockIdx.x * 256 + threadIdx.x;  // 131072
  int b = t >> 10, h = t & 1023;
  const float* g = gates + (size_t)b * 4096;
  float ig = sigmoidf_(g[h]);
  float fg = sigmoidf_(g[1024 + h]);
  float gg = tanhf(g[2048 + h]);
  float og = sigmoidf_(g[3072 + h]);
  float c1 = fg * c0[t] + ig * gg;
  float h1 = og * tanhf(c1);
  c1_out[t] = c1;
  h1_out[t] = h1;
  A3[(size_t)b * 2048 + 1024 + h] = f2bf(h1);  // second half of concat row
}

// ---------------- K4: flash attention, LDS-staged streaming (ctx read ONCE) -----------
// grid 512: b = bid>>2, chunk = bid&3 (128 rows). target read as sum of 4 K-partials.
__launch_bounds__(256, 2)
__global__ void k_attn(const float* __restrict__ ctx, const float* __restrict__ tp,
                       const unsigned char* __restrict__ mask,
                       float* __restrict__ scores, float* __restrict__ part) {
  __shared__ __align__(16) float lds[2][8 * 1024];  // 2 x 32KB
  const int b = blockIdx.x >> 2, chunk = blockIdx.x & 3;
  const int tid = threadIdx.x;
  const int wid = tid >> 6, l = tid & 63;
  float4 t4[4], w4[4];
#pragma unroll
  for (int j = 0; j < 4; ++j) {
    float4 a = {0.f, 0.f, 0.f, 0.f};
#pragma unroll
    for (int p = 0; p < 4; ++p) {
      const float4 v = *(const float4*)(tp + (size_t)p * 131072 + (size_t)b * 1024 + j * 256 + l * 4);
      a.x += v.x; a.y += v.y; a.z += v.z; a.w += v.w;
    }
    t4[j] = a;
    w4[j].x = 0.f; w4[j].y = 0.f; w4[j].z = 0.f; w4[j].w = 0.f;
  }
  float m = -INFINITY, lsum = 0.f;
  const int s0 = chunk * 128;
  const float* cb = ctx + ((size_t)b * 512 + s0) * 1024;
  const unsigned char* mk = mask + (size_t)b * 512 + s0;

  auto stage = [&](int buf, int tt) {
    const char* src = (const char*)(cb + (size_t)tt * 8192);
    char* dst = (char*)&lds[buf][0];
#pragma unroll
    for (int i = 0; i < 8; ++i) {
      const int off = i * 4096 + tid * 16;
      __builtin_amdgcn_global_load_lds((gu32_t*)(src + off), (lu32_t*)(dst + off), 16, 0, 0);
    }
  };

  stage(0, 0);
  int buf = 0;
  for (int t = 0; t < 16; ++t) {
    if (t < 15) {
      stage(buf ^ 1, t + 1);
      asm volatile("s_waitcnt vmcnt(8)" ::: "memory");  // tile t done; t+1 in flight
    } else {
      asm volatile("s_waitcnt vmcnt(0)" ::: "memory");
    }
    block_barrier();  // B1: tile t visible to all waves
#pragma unroll
    for (int rr = 0; rr < 2; ++rr) {
      const int r = wid * 2 + rr;
      const float* row = &lds[buf][r * 1024];
      float4 c0 = *(const float4*)(row + l * 4);
      float4 c1 = *(const float4*)(row + 256 + l * 4);
      float4 c2 = *(const float4*)(row + 512 + l * 4);
      float4 c3 = *(const float4*)(row + 768 + l * 4);
      float p = c0.x * t4[0].x + c0.y * t4[0].y + c0.z * t4[0].z + c0.w * t4[0].w +
                c1.x * t4[1].x + c1.y * t4[1].y + c1.z * t4[1].z + c1.w * t4[1].w +
                c2.x * t4[2].x + c2.y * t4[2].y + c2.z * t4[2].z + c2.w * t4[2].w +
                c3.x * t4[3].x + c3.y * t4[3].y + c3.z * t4[3].z + c3.w * t4[3].w;
#pragma unroll
      for (int off = 32; off > 0; off >>= 1) p += __shfl_xor(p, off);
      const int sg = t * 8 + r;
      if (mk[sg]) p = NEG_BIG;
      if (l == 0) scores[(size_t)b * 512 + s0 + sg] = p;
      float mn = fmaxf(m, p);
      float scale = __expf(m - mn);
      float e = __expf(p - mn);
      lsum = lsum * scale + e;
      w4[0].x = w4[0].x * scale + e * c0.x; w4[0].y = w4[0].y * scale + e * c0.y;
      w4[0].z = w4[0].z * scale + e * c0.z; w4[0].w = w4[0].w * scale + e * c0.w;
      w4[1].x = w4[1].x * scale + e * c1.x; w4[1].y = w4[1].y * scale + e * c1.y;
      w4[1].z = w4[1].z * scale + e * c1.z; w4[1].w = w4[1].w * scale + e * c1.w;
      w4[2].x = w4[2].x * scale + e * c2.x; w4[2].y = w4[2].y * scale + e * c2.y;
      w4[2].z = w4[2].z * scale + e * c2.z; w4[2].w = w4[2].w * scale + e * c2.w;
      w4[3].x = w4[3].x * scale + e * c3.x; w4[3].y = w4[3].y * scale + e * c3.y;
      w4[3].z = w4[3].z * scale + e * c3.z; w4[3].w = w4[3].w * scale + e * c3.w;
      m = mn;
    }
    block_barrier();  // B2: all waves done reading lds[buf] before overwrite
    buf ^= 1;
  }
  float* pp = part + ((size_t)b * 16 + (chunk * 4 + wid)) * 1028;
#pragma unroll
  for (int j = 0; j < 4; ++j) *(float4*)(pp + j * 256 + l * 4) = w4[j];
  if (l == 0) { pp[1024] = m; pp[1025] = lsum; }
}

// ------- K5: finish = exact alpha (from partial m/l) + combine partials -------
__launch_bounds__(256, 4)
__global__ void k_finish(const float* __restrict__ scores, const float* __restrict__ part,
                         float* __restrict__ alpha, short* __restrict__ A3) {
  __shared__ float sm[16], sl[16];
  int b = blockIdx.x, t = threadIdx.x;
  if (t < 16) {
    sm[t] = part[((size_t)b * 16 + t) * 1028 + 1024];
    sl[t] = part[((size_t)b * 16 + t) * 1028 + 1025];
  }
  __syncthreads();
  float M = -INFINITY;
#pragma unroll
  for (int i = 0; i < 16; ++i) M = fmaxf(M, sm[i]);
  float scl[16];
  float L = 0.f;
#pragma unroll
  for (int i = 0; i < 16; ++i) {
    scl[i] = __expf(sm[i] - M);
    L += sl[i] * scl[i];
  }
  float inv = 1.0f / L;
  float s0 = scores[(size_t)b * 512 + t];
  float s1 = scores[(size_t)b * 512 + 256 + t];
  alpha[(size_t)b * 512 + t] = __expf(s0 - M) * inv;
  alpha[(size_t)b * 512 + 256 + t] = __expf(s1 - M) * inv;
  float ax = 0.f, ay = 0.f, az = 0.f, aw = 0.f;
#pragma unroll
  for (int i = 0; i < 16; ++i) {
    const float4 w = *(const float4*)(part + ((size_t)b * 16 + i) * 1028 + t * 4);
    ax += scl[i] * w.x; ay += scl[i] * w.y; az += scl[i] * w.z; aw += scl[i] * w.w;
  }
  short4 o4;
  o4.x = f2bf(ax * inv); o4.y = f2bf(ay * inv); o4.z = f2bf(az * inv); o4.w = f2bf(aw * inv);
  *(short4*)(A3 + (size_t)b * 2048 + t * 4) = o4;
}

// ------- K6: htilde = bf16(tanh(sum of 8 wout K-partials)) -------
__global__ void k_htilde(const float* __restrict__ wp, short* __restrict__ ht) {
  int t = blockIdx.x * 256 + threadIdx.x;  // 131072
  float s = 0.f;
#pragma unroll
  for (int p = 0; p < 8; ++p) s += wp[(size_t)p * 131072 + t];
  ht[t] = f2bf(tanhf(s));
}

extern "C" void kernel_launch(void* const* d_in, const int* in_sizes, int n_in,
                              void* d_out, int out_size, void* d_ws, size_t ws_size,
                              hipStream_t stream) {
  const int* prev = (const int*)d_in[0];
  const float* h0 = (const float*)d_in[1];
  const float* c0 = (const float*)d_in[2];
  const float* ctx = (const float*)d_in[3];
  const unsigned char* mask = (const unsigned char*)d_in[4];
  const float* emb = (const float*)d_in[5];
  const float* W_ih = (const float*)d_in[6];
  const float* W_hh = (const float*)d_in[7];
  const float* b_ih = (const float*)d_in[8];
  const float* b_hh = (const float*)d_in[9];
  const float* W_in = (const float*)d_in[10];
  const float* W_out = (const float*)d_in[11];
  const float* W_dec = (const float*)d_in[12];
  const float* b_dec = (const float*)d_in[13];

  float* out_h1 = (float*)d_out;            // 128*1024
  float* out_c1 = out_h1 + 128 * 1024;      // 128*1024
  float* out_alpha = out_c1 + 128 * 1024;   // 128*512
  float* out_logit = out_alpha + 128 * 512; // 128*32000

  char* ws = (char*)d_ws;
  short* A3 = (short*)(ws + 0x000000);      // 128x2048 bf16 [weighted | h1] (512KB)
  float* scores = (float*)(ws + 0x100000);  // 128x512 f32 (256KB)
  float* tp = (float*)(ws + 0x200000);      // 4 x 128x1024 f32 target partials (2MB)
  float* part = (float*)(ws + 0x400000);    // 128x16x1028 f32 (8.42MB)
  float* wp = (float*)(ws + 0xD00000);      // 8 x 128x1024 f32 wout partials (4MB)
  float* gates = (float*)(ws + 0x1100000);  // 128x4096 f32 (2MB)
  short* A1 = (short*)(ws + 0x1300000);     // 128x1536 bf16 (384KB)
  short* htilde = (short*)(ws + 0x1400000); // 128x1024 bf16 (256KB)

  // 1) pack gather+h0 operand
  k_pack_a1<<<768, 256, 0, stream>>>(prev, emb, h0, A1);
  // 2) gates = [emb|h0] @ [W_ih|W_hh]^T + b_ih + b_hh (N=4096, K=1536, 256 blocks)
  k_gemm<128, 1, 0><<<dim3(256, 1, 1), 256, 0, stream>>>(
      A1, 1536, W_ih, 512, 512, W_hh, 1024, 1536, b_ih, b_hh, gates, nullptr, 4096, 0, 0);
  // 3) LSTM cell -> h_1, c_1 (+ bf16 h1 into A3 second half)
  k_lstm<<<512, 256, 0, stream>>>(gates, c0, out_h1, out_c1, A3);
  // 4) target partials = h1 @ W_in^T, split-K x4 (256 blocks, 64KB W/block)
  k_gemm<128, 1, 0><<<dim3(64, 1, 4), 256, 0, stream>>>(
      A3 + 1024, 2048, W_in, 1024, 1 << 30, W_in, 1024, 256, nullptr, nullptr, tp, nullptr,
      1024, 256, (size_t)131072);
  // 5) flash attention over ctx (read once); target = sum of 4 partials on load
  k_attn<<<512, 256, 0, stream>>>(ctx, tp, mask, scores, part);
  // 6) alpha + combine partials -> weighted (bf16 into A3 first half)
  k_finish<<<128, 256, 0, stream>>>(scores, part, out_alpha, A3);
  // 7) wout partials = [weighted|h1] @ W_out^T, split-K x8 (512 blocks, 64KB W/block)
  k_gemm<128, 1, 0><<<dim3(64, 1, 8), 256, 0, stream>>>(
      A3, 2048, W_out, 2048, 1 << 30, W_out, 2048, 256, nullptr, nullptr, wp, nullptr,
      1024, 256, (size_t)131072);
  // 8) htilde = tanh(sum of wout partials), bf16
  k_htilde<<<512, 256, 0, stream>>>(wp, htilde);
  // 9) logit = h_tilde @ W_dec^T + b_dec (N=32000, K=1024, 500 blocks)
  k_gemm<128, 4, 0><<<dim3(500, 1, 1), 256, 0, stream>>>(
      htilde, 1024, W_dec, 1024, 1024, W_dec, 1024, 1024, b_dec, nullptr, out_logit, nullptr,
      32000, 0, 0);
}